// Round 7
// baseline (194.885 us; speedup 1.0000x reference)
//
#include <hip/hip_runtime.h>
#include <hip/hip_bf16.h>

// GAT on MI355X. Inputs fp32 (+ int32 adj); output fp32 [8 | 4096*8].
//  kA0: W -> Wt bf16; WhT rows 8..15 init (col8=ones); adj -> 1-bit mask (2 MB);
//       mhat/out init. grid 2048x256.
//  kA : Wh = x @ W via MFMA (16 waves); epilogue: WhT bf16, scores pre-scaled by
//       log2(e), atomicMax mhat.
//  kD : MFMA attention, double-buffered 512-j LDS tiles (WhT only in LDS; sd/mask
//       direct global->reg, issued before the asm fence so they can't re-sink),
//       uniform 4x gll16/wave staging, counted vmcnt(4), 2 barriers/tile x 8 tiles.
//       Epilogue: head-mean -> neF + fused log_softmax + w_lin -> atomicAdd out.
typedef __attribute__((ext_vector_type(8))) short bf16x8;
typedef __attribute__((ext_vector_type(4))) float f32x4;

#define NN 4096
#define NC 8
#define L2EF 1.4426950408889634f

__device__ __forceinline__ short f2bf(float f) {
  __hip_bfloat16 h = __float2bfloat16(f);
  return *reinterpret_cast<short*>(&h);
}
__device__ __forceinline__ unsigned fenc(float v) {
  int b = __float_as_int(v);
  return (b >= 0) ? ((unsigned)b | 0x80000000u) : (unsigned)(~b);
}
__device__ __forceinline__ float fdec(unsigned k) {
  int b = (k & 0x80000000u) ? (int)(k & 0x7FFFFFFFu) : ~(int)k;
  return __int_as_float(b);
}
__device__ __forceinline__ bool is_adj(const void* p) {
  const unsigned* u = (const unsigned*)p;
  unsigned m = u[0] | u[1] | u[2] | u[3] | u[100] | u[1000];
  return m <= 1u;
}
__device__ __forceinline__ void gll16(const void* g, void* l) {
  __builtin_amdgcn_global_load_lds((const __attribute__((address_space(1))) void*)g,
                                   (__attribute__((address_space(3))) void*)l, 16, 0, 0);
}

// ---------- kA0: Wt transform + WhT init + adj bitmask pack + inits ----------
__global__ __launch_bounds__(256) void kA0(const float* __restrict__ W, short* __restrict__ Wt,
                                           short* __restrict__ WhT, const float* __restrict__ blin,
                                           float* __restrict__ outF, unsigned* __restrict__ mhatU,
                                           const void* __restrict__ c0, const void* __restrict__ c1,
                                           unsigned* __restrict__ maskW) {
  const int* adj = (const int*)(is_adj(c0) ? c0 : c1);
  int t = threadIdx.x;
  int u = blockIdx.x * 256 + t;              // 524288
  if (u < 131072) {
    int h = u >> 15, r = u & 32767, f = r >> 3, o = r & 7;
    Wt[(size_t)(h * 8 + o) * NN + f] = f2bf(W[u]);
    int n2 = 8 + (r >> 12), j2 = r & 4095;
    WhT[((size_t)(h * 16 + n2)) * NN + j2] = (n2 == 8) ? (short)0x3F80 : (short)0;
  }
  {
    const int4* p = (const int4*)(adj + ((size_t)u << 5));   // u*32 ints, linear
    unsigned bits = 0u;
#pragma unroll
    for (int i = 0; i < 8; ++i) {
      int4 v = p[i];
      bits |= (v.x > 0 ? 1u : 0u) << (4 * i);
      bits |= (v.y > 0 ? 1u : 0u) << (4 * i + 1);
      bits |= (v.z > 0 ? 1u : 0u) << (4 * i + 2);
      bits |= (v.w > 0 ? 1u : 0u) << (4 * i + 3);
    }
    maskW[u] = bits;                          // word u: row u>>7, bits j = (u&127)*32+e
  }
  if (u < 4) mhatU[u] = 0u;
  if (u >= 8 && u < 16) outF[u - 8] = blin[0];
}

// ---------- kA: 256 blocks x 1024 thr (16 waves). wave w: k in [w*256,(w+1)*256) ----------
__global__ __launch_bounds__(1024) void kA(const void* __restrict__ c0, const void* __restrict__ c1,
                                           const short* __restrict__ Wt,
                                           short* __restrict__ WhT, float* __restrict__ ssrc,
                                           float* __restrict__ sdst, const float* __restrict__ a,
                                           unsigned* __restrict__ mhatU) {
  const float* x = (const float*)(is_adj(c0) ? c1 : c0);
  int m0 = blockIdx.x * 16;
  int t = threadIdx.x;
  int w = t >> 6, lane = t & 63;
  int mr = lane & 15, q = lane >> 4;
  const f32x4*  ap  = (const f32x4*)(x + (size_t)(m0 + mr) * NN + w * 256 + q * 8);
  const bf16x8* b0p = (const bf16x8*)(Wt + (size_t)mr        * NN + w * 256 + q * 8);
  const bf16x8* b1p = (const bf16x8*)(Wt + (size_t)(16 + mr) * NN + w * 256 + q * 8);
  f32x4 xs[16];
#pragma unroll
  for (int kk = 0; kk < 8; ++kk) {
    xs[2 * kk]     = ap[kk * 8];
    xs[2 * kk + 1] = ap[kk * 8 + 1];
  }
  f32x4 acc0 = {0.f, 0.f, 0.f, 0.f}, acc1 = {0.f, 0.f, 0.f, 0.f};
#pragma unroll
  for (int kk = 0; kk < 8; ++kk) {
    bf16x8 b0 = b0p[kk * 4];
    bf16x8 b1 = b1p[kk * 4];
    bf16x8 af;
#pragma unroll
    for (int e = 0; e < 4; ++e) {
      af[e]     = f2bf(xs[2 * kk][e]);
      af[4 + e] = f2bf(xs[2 * kk + 1][e]);
    }
    acc0 = __builtin_amdgcn_mfma_f32_16x16x32_bf16(af, b0, acc0, 0, 0, 0);
    acc1 = __builtin_amdgcn_mfma_f32_16x16x32_bf16(af, b1, acc1, 0, 0, 0);
  }
  __shared__ float red[16][16][32];
  __shared__ float whole[16][32];
#pragma unroll
  for (int r = 0; r < 4; ++r) {
    red[w][q * 4 + r][mr]      = acc0[r];
    red[w][q * 4 + r][16 + mr] = acc1[r];
  }
  __syncthreads();
  if (t < 512) {
    int m = t >> 5, c = t & 31;
    float s = 0.f;
#pragma unroll
    for (int ww = 0; ww < 16; ++ww) s += red[ww][m][c];
    whole[m][c] = s;
    int h = c >> 3, o = c & 7;
    WhT[((size_t)(h * 16 + o)) * NN + (m0 + m)] = f2bf(s);
  }
  __syncthreads();
  if (t < 64) {
    int h = t >> 4, m = t & 15;
    float s1 = 0.f, s2 = 0.f;
#pragma unroll
    for (int o = 0; o < 8; ++o) {
      float v = whole[m][h * 8 + o];
      s1 += v * a[h * 16 + o];
      s2 += v * a[h * 16 + 8 + o];
    }
    ssrc[h * NN + m0 + m] = s1 * L2EF;     // pre-scaled by log2(e)
    sdst[h * NN + m0 + m] = s2 * L2EF;
    float mx = s2 * L2EF;
#pragma unroll
    for (int mm = 1; mm <= 8; mm <<= 1) mx = fmaxf(mx, __shfl_xor(mx, mm));
    if ((t & 15) == 0) atomicMax(&mhatU[h], fenc(mx));
  }
}

// ---------- kD: 256 blocks x 1024 thr. dbuf 512-j tiles, counted vmcnt(4) ----------
// wave w: head h=w&3, j-quarter jq=w>>2 (128 j/tile/wave = 4 chunks of 32).
// LDS holds ONLY WhT slices (rows XOR-swizzled via pre-swizzled source; read
// back with same XOR -> 2-way conflicts, free). sd + mask come as direct
// global->reg loads at iteration top (L2-resident), pinned before the
// memory-clobber vmcnt asm so the compiler cannot re-sink them.
__global__ __launch_bounds__(1024) void kD(const unsigned* __restrict__ maskW,
                                           const short* __restrict__ WhT,
                                           const float* __restrict__ ssrcg, const float* __restrict__ sdstg,
                                           const unsigned* __restrict__ mhatU,
                                           const float* __restrict__ wlin,
                                           float* __restrict__ outF, float* __restrict__ neF) {
  __shared__ short whS[2][64][512];     // 128 KB: row r = h*16+o, 1024 B, swizzled
  __shared__ float red[16][16][10];     // 10 KB
  __shared__ float ps[2][8];
  int t = threadIdx.x;
  int w = t >> 6, lane = t & 63;
  int h = w & 3, jq = w >> 2;
  int m = lane & 15, q = lane >> 4;
  int i0 = blockIdx.x * 16;
  unsigned km = (unsigned)((m & 7) << 4);
  int r0 = 4 * w;

  float mh  = fdec(mhatU[h]);                // pre-scaled
  float ssr = ssrcg[h * NN + i0 + m];        // pre-scaled
  float tb  = ssr + mh;
  float eb  = fmaxf(tb, 0.2f * tb);
  const float*    sdp = sdstg + h * NN + jq * 128 + q * 8;
  const unsigned* mkp = maskW + (size_t)(i0 + m) * 128 + jq * 4;
  const char*     whRow = (const char*)whS + (size_t)(h * 16 + m) * 1024;
  f32x4 acc = {0.f, 0.f, 0.f, 0.f};

#define STAGE(BUF, JT)                                                        \
  _Pragma("unroll")                                                           \
  for (int i = 0; i < 4; ++i) {                                               \
    int r = r0 + i;                                                           \
    const char* src = (const char*)(WhT + (size_t)r * NN + (JT) * 512)        \
                      + ((lane * 16) ^ ((r & 7) << 4));                       \
    gll16(src, (char*)whS + (BUF) * 65536 + r * 1024);                        \
  }

#define CHUNK(BUF, C, S0, S1, MW)                                             \
  { unsigned mbyte = ((MW) >> (q * 8)) & 255u;                                \
    bf16x8 bv = *(const bf16x8*)(whRow + (BUF) * 65536 +                      \
                 (((unsigned)(jq * 256 + (C) * 64 + q * 16)) ^ km));          \
    bf16x8 af;                                                                \
    _Pragma("unroll")                                                         \
    for (int e = 0; e < 4; ++e) {                                             \
      float tt = ssr + S0[e];                                                 \
      float ee = fmaxf(tt, 0.2f * tt);                                        \
      float wv = __builtin_amdgcn_exp2f(ee - eb);                             \
      af[e] = (mbyte & (1u << e)) ? f2bf(wv) : (short)0;                      \
    }                                                                         \
    _Pragma("unroll")                                                         \
    for (int e = 0; e < 4; ++e) {                                             \
      float tt = ssr + S1[e];                                                 \
      float ee = fmaxf(tt, 0.2f * tt);                                        \
      float wv = __builtin_amdgcn_exp2f(ee - eb);                             \
      af[4 + e] = (mbyte & (16u << e)) ? f2bf(wv) : (short)0;                 \
    }                                                                         \
    acc = __builtin_amdgcn_mfma_f32_16x16x32_bf16(af, bv, acc, 0, 0, 0);      \
  }

  STAGE(0, 0)
#pragma unroll 2
  for (int jt = 0; jt < 8; ++jt) {
    const int buf = jt & 1;
    // sd/mask loads for THIS tile -> registers (before the fence; cannot sink)
    const float* sdt = sdp + jt * 512;
    f32x4 s00 = *(const f32x4*)(sdt);
    f32x4 s01 = *(const f32x4*)(sdt + 4);
    f32x4 s10 = *(const f32x4*)(sdt + 32);
    f32x4 s11 = *(const f32x4*)(sdt + 36);
    f32x4 s20 = *(const f32x4*)(sdt + 64);
    f32x4 s21 = *(const f32x4*)(sdt + 68);
    f32x4 s30 = *(const f32x4*)(sdt + 96);
    f32x4 s31 = *(const f32x4*)(sdt + 100);
    int4  mk4 = *(const int4*)(mkp + jt * 16);
    if (jt < 7) { STAGE(buf ^ 1, jt + 1) }
    if (jt < 7) { asm volatile("s_waitcnt vmcnt(4)" ::: "memory"); }
    else        { asm volatile("s_waitcnt vmcnt(0)" ::: "memory"); }
    __builtin_amdgcn_s_barrier();
    CHUNK(buf, 0, s00, s01, (unsigned)mk4.x)
    CHUNK(buf, 1, s10, s11, (unsigned)mk4.y)
    CHUNK(buf, 2, s20, s21, (unsigned)mk4.z)
    CHUNK(buf, 3, s30, s31, (unsigned)mk4.w)
    __builtin_amdgcn_s_barrier();
  }
#undef STAGE
#undef CHUNK

  if (m < 9) {
#pragma unroll
    for (int r = 0; r < 4; ++r) red[w][q * 4 + r][m] = acc[r];
  }
  __syncthreads();
  if (t < 128) {
    int i = t >> 3, o = t & 7;
    float tot = 0.f;
#pragma unroll
    for (int hh = 0; hh < 4; ++hh) {
      float s = 0.f, l = 0.f;
#pragma unroll
      for (int jj = 0; jj < 4; ++jj) {
        int w2 = jj * 4 + hh;
        s += red[w2][i][o];
        l += red[w2][i][8];
      }
      tot += s / l;
    }
    float ne = 0.25f * tot;
    neF[(size_t)(i0 + i) * NC + o] = ne;
    float mx = ne;
#pragma unroll
    for (int mm = 1; mm <= 4; mm <<= 1) mx = fmaxf(mx, __shfl_xor(mx, mm));
    float ex = __expf(ne - mx);
    float s8 = ex;
#pragma unroll
    for (int mm = 1; mm <= 4; mm <<= 1) s8 += __shfl_xor(s8, mm);
    float ln = mx + __logf(s8);
    float p = (ne - ln) * wlin[i0 + i];
#pragma unroll
    for (int mm = 8; mm <= 32; mm <<= 1) p += __shfl_xor(p, mm);
    if ((t & 63) < 8) ps[t >> 6][t & 7] = p;
  }
  __syncthreads();
  if (t < 8) atomicAdd(&outF[t], ps[0][t] + ps[1][t]);
}

extern "C" void kernel_launch(void* const* d_in, const int* in_sizes, int n_in,
                              void* d_out, int out_size, void* d_ws, size_t ws_size,
                              hipStream_t stream) {
  const void* big0 = nullptr; const void* big1 = nullptr;
  const float* W = nullptr; const float* a = nullptr;
  const float* wlin = nullptr; const float* blin = nullptr;
  for (int idx = 0; idx < n_in; ++idx) {
    int sz = in_sizes[idx];
    if (sz == NN * NN)          { if (!big0) big0 = d_in[idx]; else big1 = d_in[idx]; }
    else if (sz == 4 * NN * NC) W    = (const float*)d_in[idx];
    else if (sz == 64)          a    = (const float*)d_in[idx];
    else if (sz == NN)          wlin = (const float*)d_in[idx];
    else if (sz == 1)           blin = (const float*)d_in[idx];
  }
  float* outF = (float*)d_out;       // fp32: [8] out | [4096][8] node_embeddings
  float* neF  = outF + 8;

  char* ws = (char*)d_ws;
  short*    Wt    = (short*)(ws + 0);         // 262144 B
  short*    WhT   = (short*)(ws + 262144);    // 524288 B : [4h*16][4096] bf16 (row h*16+8 = ones)
  float*    ssrc  = (float*)(ws + 786432);    // 65536 B (pre-scaled by log2 e)
  float*    sdst  = (float*)(ws + 851968);    // 65536 B (pre-scaled by log2 e)
  unsigned* mhatU = (unsigned*)(ws + 917504); // 16 B
  unsigned* maskW = (unsigned*)(ws + 1048576);// 2 MB : [4096 rows][128 words] adj bitmask

  kA0<<<2048, 256, 0, stream>>>(W, Wt, WhT, blin, outF, mhatU, big0, big1, maskW);
  kA <<<256, 1024, 0, stream>>>(big0, big1, Wt, WhT, ssrc, sdst, a, mhatU);
  kD <<<256, 1024, 0, stream>>>(maskW, WhT, ssrc, sdst, mhatU, wlin, outF, neF);
}

// Round 8
// 194.297 us; speedup vs baseline: 1.0030x; 1.0030x over previous
//
#include <hip/hip_runtime.h>
#include <hip/hip_bf16.h>

// GAT on MI355X. Inputs fp32 (+ int32 adj); output fp32 [8 | 4096*8].
//  kInit: W -> Wt bf16; WhT rows 8..15 init (col8=ones); mhat/out init.
//  kA  : Wh = x @ W via MFMA (16 waves); + adj -> 1-bit mask pack (overlapped
//        with epilogue); epilogue: WhT bf16, scores pre-scaled by log2(e),
//        atomicMax mhat.
//  kD  : MFMA attention, dbuf 512-j LDS tiles (WhT via gll16, swizzled),
//        sd/mask PREFETCHED ONE TILE AHEAD in registers, counted vmcnt(13),
//        2 raw barriers/tile x 8 tiles. Epilogue: head-mean -> neF + fused
//        log_softmax + w_lin -> atomicAdd out.
typedef __attribute__((ext_vector_type(8))) short bf16x8;
typedef __attribute__((ext_vector_type(4))) float f32x4;

#define NN 4096
#define NC 8
#define L2EF 1.4426950408889634f

__device__ __forceinline__ short f2bf(float f) {
  __hip_bfloat16 h = __float2bfloat16(f);
  return *reinterpret_cast<short*>(&h);
}
__device__ __forceinline__ unsigned fenc(float v) {
  int b = __float_as_int(v);
  return (b >= 0) ? ((unsigned)b | 0x80000000u) : (unsigned)(~b);
}
__device__ __forceinline__ float fdec(unsigned k) {
  int b = (k & 0x80000000u) ? (int)(k & 0x7FFFFFFFu) : ~(int)k;
  return __int_as_float(b);
}
__device__ __forceinline__ bool is_adj(const void* p) {
  const unsigned* u = (const unsigned*)p;
  unsigned m = u[0] | u[1] | u[2] | u[3] | u[100] | u[1000];
  return m <= 1u;
}
__device__ __forceinline__ void gll16(const void* g, void* l) {
  __builtin_amdgcn_global_load_lds((const __attribute__((address_space(1))) void*)g,
                                   (__attribute__((address_space(3))) void*)l, 16, 0, 0);
}

// ---------- kInit: Wt transform + WhT ones-rows + misc inits ----------
__global__ __launch_bounds__(256) void kInit(const float* __restrict__ W, short* __restrict__ Wt,
                                             short* __restrict__ WhT, const float* __restrict__ blin,
                                             float* __restrict__ outF, unsigned* __restrict__ mhatU) {
  int t = threadIdx.x;
  int u = blockIdx.x * 256 + t;              // 131072
  int h = u >> 15, r = u & 32767, f = r >> 3, o = r & 7;
  Wt[(size_t)(h * 8 + o) * NN + f] = f2bf(W[u]);
  int n2 = 8 + (r >> 12), j2 = r & 4095;
  WhT[((size_t)(h * 16 + n2)) * NN + j2] = (n2 == 8) ? (short)0x3F80 : (short)0;
  if (u < 4) mhatU[u] = 0u;
  if (u >= 8 && u < 16) outF[u - 8] = blin[0];
}

// ---------- kA: 256 blocks x 1024 thr (16 waves). wave w: k in [w*256,(w+1)*256) ----------
// + adj bitmask pack fused: 2 words/thread, loads issued after MFMA loop (latency
//   hides under LDS-reduce epilogue), packed+stored at kernel end.
__global__ __launch_bounds__(1024) void kA(const void* __restrict__ c0, const void* __restrict__ c1,
                                           const short* __restrict__ Wt,
                                           short* __restrict__ WhT, float* __restrict__ ssrc,
                                           float* __restrict__ sdst, const float* __restrict__ a,
                                           unsigned* __restrict__ mhatU, unsigned* __restrict__ maskW) {
  bool c0a = is_adj(c0);
  const float* x   = (const float*)(c0a ? c1 : c0);
  const int*   adj = (const int*)(c0a ? c0 : c1);
  int m0 = blockIdx.x * 16;
  int t = threadIdx.x;
  int w = t >> 6, lane = t & 63;
  int mr = lane & 15, q = lane >> 4;
  const f32x4*  ap  = (const f32x4*)(x + (size_t)(m0 + mr) * NN + w * 256 + q * 8);
  const bf16x8* b0p = (const bf16x8*)(Wt + (size_t)mr        * NN + w * 256 + q * 8);
  const bf16x8* b1p = (const bf16x8*)(Wt + (size_t)(16 + mr) * NN + w * 256 + q * 8);
  f32x4 xs[16];
#pragma unroll
  for (int kk = 0; kk < 8; ++kk) {
    xs[2 * kk]     = ap[kk * 8];
    xs[2 * kk + 1] = ap[kk * 8 + 1];
  }
  f32x4 acc0 = {0.f, 0.f, 0.f, 0.f}, acc1 = {0.f, 0.f, 0.f, 0.f};
#pragma unroll
  for (int kk = 0; kk < 8; ++kk) {
    bf16x8 b0 = b0p[kk * 4];
    bf16x8 b1 = b1p[kk * 4];
    bf16x8 af;
#pragma unroll
    for (int e = 0; e < 4; ++e) {
      af[e]     = f2bf(xs[2 * kk][e]);
      af[4 + e] = f2bf(xs[2 * kk + 1][e]);
    }
    acc0 = __builtin_amdgcn_mfma_f32_16x16x32_bf16(af, b0, acc0, 0, 0, 0);
    acc1 = __builtin_amdgcn_mfma_f32_16x16x32_bf16(af, b1, acc1, 0, 0, 0);
  }
  // adj pack loads: issue now (xs dead -> regs reuse), consume at kernel end.
  __builtin_amdgcn_sched_barrier(0);
  size_t gtid = (size_t)blockIdx.x * 1024 + t;          // 262144 threads
  const int4* ap4 = (const int4*)(adj + (gtid << 6));   // 64 ints/thread
  int4 av[16];
#pragma unroll
  for (int i = 0; i < 16; ++i) av[i] = ap4[i];
  __builtin_amdgcn_sched_barrier(0);

  __shared__ float red[16][16][32];
  __shared__ float whole[16][32];
#pragma unroll
  for (int r = 0; r < 4; ++r) {
    red[w][q * 4 + r][mr]      = acc0[r];
    red[w][q * 4 + r][16 + mr] = acc1[r];
  }
  __syncthreads();
  if (t < 512) {
    int m = t >> 5, c = t & 31;
    float s = 0.f;
#pragma unroll
    for (int ww = 0; ww < 16; ++ww) s += red[ww][m][c];
    whole[m][c] = s;
    int h = c >> 3, o = c & 7;
    WhT[((size_t)(h * 16 + o)) * NN + (m0 + m)] = f2bf(s);
  }
  __syncthreads();
  if (t < 64) {
    int h = t >> 4, m = t & 15;
    float s1 = 0.f, s2 = 0.f;
#pragma unroll
    for (int o = 0; o < 8; ++o) {
      float v = whole[m][h * 8 + o];
      s1 += v * a[h * 16 + o];
      s2 += v * a[h * 16 + 8 + o];
    }
    ssrc[h * NN + m0 + m] = s1 * L2EF;     // pre-scaled by log2(e)
    sdst[h * NN + m0 + m] = s2 * L2EF;
    float mx = s2 * L2EF;
#pragma unroll
    for (int mm = 1; mm <= 8; mm <<= 1) mx = fmaxf(mx, __shfl_xor(mx, mm));
    if ((t & 15) == 0) atomicMax(&mhatU[h], fenc(mx));
  }
  // pack + store mask words (av ready by now; latency hidden under epilogue)
  unsigned w0 = 0u, w1 = 0u;
#pragma unroll
  for (int i = 0; i < 8; ++i) {
    w0 |= (av[i].x > 0 ? 1u : 0u) << (4 * i);
    w0 |= (av[i].y > 0 ? 1u : 0u) << (4 * i + 1);
    w0 |= (av[i].z > 0 ? 1u : 0u) << (4 * i + 2);
    w0 |= (av[i].w > 0 ? 1u : 0u) << (4 * i + 3);
    w1 |= (av[8 + i].x > 0 ? 1u : 0u) << (4 * i);
    w1 |= (av[8 + i].y > 0 ? 1u : 0u) << (4 * i + 1);
    w1 |= (av[8 + i].z > 0 ? 1u : 0u) << (4 * i + 2);
    w1 |= (av[8 + i].w > 0 ? 1u : 0u) << (4 * i + 3);
  }
  maskW[2 * gtid]     = w0;
  maskW[2 * gtid + 1] = w1;
}

// ---------- kD: 256 blocks x 1024 thr. dbuf 512-j tiles, vmcnt(13) ----------
// wave w: head h=w&3, j-quarter jq=w>>2 (128 j/tile/wave = 4 chunks of 32).
// LDS holds ONLY WhT slices (rows XOR-swizzled via pre-swizzled source).
// sd + mask prefetched ONE TILE AHEAD into double-buffered registers: per iter
// issue 9 reg loads (jt+1) + 4 gll (jt+1) -> vmcnt(13) drains exactly tile jt's
// 9+4, leaving 13 in flight across the barrier.
__global__ __launch_bounds__(1024) void kD(const unsigned* __restrict__ maskW,
                                           const short* __restrict__ WhT,
                                           const float* __restrict__ ssrcg, const float* __restrict__ sdstg,
                                           const unsigned* __restrict__ mhatU,
                                           const float* __restrict__ wlin,
                                           float* __restrict__ outF, float* __restrict__ neF) {
  __shared__ short whS[2][64][512];     // 128 KB: row r = h*16+o, 1024 B, swizzled
  __shared__ float red[16][16][10];     // 10 KB
  __shared__ float ps[2][8];
  int t = threadIdx.x;
  int w = t >> 6, lane = t & 63;
  int h = w & 3, jq = w >> 2;
  int m = lane & 15, q = lane >> 4;
  int i0 = blockIdx.x * 16;
  unsigned km = (unsigned)((m & 7) << 4);
  int r0 = 4 * w;

  float mh  = fdec(mhatU[h]);                // pre-scaled
  float ssr = ssrcg[h * NN + i0 + m];        // pre-scaled
  float tb  = ssr + mh;
  float eb  = fmaxf(tb, 0.2f * tb);
  const float*    sdp = sdstg + h * NN + jq * 128 + q * 8;
  const unsigned* mkp = maskW + (size_t)(i0 + m) * 128 + jq * 4;
  const char*     whRow = (const char*)whS + (size_t)(h * 16 + m) * 1024;
  f32x4 acc = {0.f, 0.f, 0.f, 0.f};
  f32x4 sdR[2][8];
  int4  mkR[2];

#define LOADSD(S, JT)                                                         \
  { const float* sdt = sdp + (JT) * 512;                                      \
    sdR[S][0] = *(const f32x4*)(sdt);       sdR[S][1] = *(const f32x4*)(sdt + 4);   \
    sdR[S][2] = *(const f32x4*)(sdt + 32);  sdR[S][3] = *(const f32x4*)(sdt + 36);  \
    sdR[S][4] = *(const f32x4*)(sdt + 64);  sdR[S][5] = *(const f32x4*)(sdt + 68);  \
    sdR[S][6] = *(const f32x4*)(sdt + 96);  sdR[S][7] = *(const f32x4*)(sdt + 100); \
    mkR[S] = *(const int4*)(mkp + (JT) * 16); }

#define STAGE(BUF, JT)                                                        \
  _Pragma("unroll")                                                           \
  for (int i = 0; i < 4; ++i) {                                               \
    int r = r0 + i;                                                           \
    const char* src = (const char*)(WhT + (size_t)r * NN + (JT) * 512)        \
                      + ((lane * 16) ^ ((r & 7) << 4));                       \
    gll16(src, (char*)whS + (BUF) * 65536 + r * 1024);                        \
  }

#define CHUNK(BUF, C, S0, S1, MW)                                             \
  { unsigned mbyte = ((MW) >> (q * 8)) & 255u;                                \
    bf16x8 bv = *(const bf16x8*)(whRow + (BUF) * 65536 +                      \
                 (((unsigned)(jq * 256 + (C) * 64 + q * 16)) ^ km));          \
    bf16x8 af;                                                                \
    _Pragma("unroll")                                                         \
    for (int e = 0; e < 4; ++e) {                                             \
      float tt = ssr + S0[e];                                                 \
      float ee = fmaxf(tt, 0.2f * tt);                                        \
      float wv = __builtin_amdgcn_exp2f(ee - eb);                             \
      af[e] = (mbyte & (1u << e)) ? f2bf(wv) : (short)0;                      \
    }                                                                         \
    _Pragma("unroll")                                                         \
    for (int e = 0; e < 4; ++e) {                                             \
      float tt = ssr + S1[e];                                                 \
      float ee = fmaxf(tt, 0.2f * tt);                                        \
      float wv = __builtin_amdgcn_exp2f(ee - eb);                             \
      af[4 + e] = (mbyte & (16u << e)) ? f2bf(wv) : (short)0;                 \
    }                                                                         \
    acc = __builtin_amdgcn_mfma_f32_16x16x32_bf16(af, bv, acc, 0, 0, 0);      \
  }

  LOADSD(0, 0)
  STAGE(0, 0)
#pragma unroll 2
  for (int jt = 0; jt < 7; ++jt) {
    const int buf = jt & 1;
    LOADSD(buf ^ 1, jt + 1)
    STAGE(buf ^ 1, jt + 1)
    asm volatile("s_waitcnt vmcnt(13)" ::: "memory");
    __builtin_amdgcn_s_barrier();
    CHUNK(buf, 0, sdR[buf][0], sdR[buf][1], (unsigned)mkR[buf].x)
    CHUNK(buf, 1, sdR[buf][2], sdR[buf][3], (unsigned)mkR[buf].y)
    CHUNK(buf, 2, sdR[buf][4], sdR[buf][5], (unsigned)mkR[buf].z)
    CHUNK(buf, 3, sdR[buf][6], sdR[buf][7], (unsigned)mkR[buf].w)
    __builtin_amdgcn_s_barrier();
  }
  asm volatile("s_waitcnt vmcnt(0)" ::: "memory");
  __builtin_amdgcn_s_barrier();
  CHUNK(1, 0, sdR[1][0], sdR[1][1], (unsigned)mkR[1].x)
  CHUNK(1, 1, sdR[1][2], sdR[1][3], (unsigned)mkR[1].y)
  CHUNK(1, 2, sdR[1][4], sdR[1][5], (unsigned)mkR[1].z)
  CHUNK(1, 3, sdR[1][6], sdR[1][7], (unsigned)mkR[1].w)
#undef LOADSD
#undef STAGE
#undef CHUNK

  if (m < 9) {
#pragma unroll
    for (int r = 0; r < 4; ++r) red[w][q * 4 + r][m] = acc[r];
  }
  __syncthreads();
  if (t < 128) {
    int i = t >> 3, o = t & 7;
    float tot = 0.f;
#pragma unroll
    for (int hh = 0; hh < 4; ++hh) {
      float s = 0.f, l = 0.f;
#pragma unroll
      for (int jj = 0; jj < 4; ++jj) {
        int w2 = jj * 4 + hh;
        s += red[w2][i][o];
        l += red[w2][i][8];
      }
      tot += s / l;
    }
    float ne = 0.25f * tot;
    neF[(size_t)(i0 + i) * NC + o] = ne;
    float mx = ne;
#pragma unroll
    for (int mm = 1; mm <= 4; mm <<= 1) mx = fmaxf(mx, __shfl_xor(mx, mm));
    float ex = __expf(ne - mx);
    float s8 = ex;
#pragma unroll
    for (int mm = 1; mm <= 4; mm <<= 1) s8 += __shfl_xor(s8, mm);
    float ln = mx + __logf(s8);
    float p = (ne - ln) * wlin[i0 + i];
#pragma unroll
    for (int mm = 8; mm <= 32; mm <<= 1) p += __shfl_xor(p, mm);
    if ((t & 63) < 8) ps[t >> 6][t & 7] = p;
  }
  __syncthreads();
  if (t < 8) atomicAdd(&outF[t], ps[0][t] + ps[1][t]);
}

extern "C" void kernel_launch(void* const* d_in, const int* in_sizes, int n_in,
                              void* d_out, int out_size, void* d_ws, size_t ws_size,
                              hipStream_t stream) {
  const void* big0 = nullptr; const void* big1 = nullptr;
  const float* W = nullptr; const float* a = nullptr;
  const float* wlin = nullptr; const float* blin = nullptr;
  for (int idx = 0; idx < n_in; ++idx) {
    int sz = in_sizes[idx];
    if (sz == NN * NN)          { if (!big0) big0 = d_in[idx]; else big1 = d_in[idx]; }
    else if (sz == 4 * NN * NC) W    = (const float*)d_in[idx];
    else if (sz == 64)          a    = (const float*)d_in[idx];
    else if (sz == NN)          wlin = (const float*)d_in[idx];
    else if (sz == 1)           blin = (const float*)d_in[idx];
  }
  float* outF = (float*)d_out;       // fp32: [8] out | [4096][8] node_embeddings
  float* neF  = outF + 8;

  char* ws = (char*)d_ws;
  short*    Wt    = (short*)(ws + 0);         // 262144 B
  short*    WhT   = (short*)(ws + 262144);    // 524288 B : [4h*16][4096] bf16 (row h*16+8 = ones)
  float*    ssrc  = (float*)(ws + 786432);    // 65536 B (pre-scaled by log2 e)
  float*    sdst  = (float*)(ws + 851968);    // 65536 B (pre-scaled by log2 e)
  unsigned* mhatU = (unsigned*)(ws + 917504); // 16 B
  unsigned* maskW = (unsigned*)(ws + 1048576);// 2 MB : [4096 rows][128 words] adj bitmask

  kInit<<<512, 256, 0, stream>>>(W, Wt, WhT, blin, outF, mhatU);
  kA   <<<256, 1024, 0, stream>>>(big0, big1, Wt, WhT, ssrc, sdst, a, mhatU, maskW);
  kD   <<<256, 1024, 0, stream>>>(maskW, WhT, ssrc, sdst, mhatU, wlin, outF, neF);
}